// Round 5
// baseline (316.411 us; speedup 1.0000x reference)
//
#include <hip/hip_runtime.h>
#include <hip/hip_bf16.h>

typedef unsigned short u16;
typedef short short8_t __attribute__((ext_vector_type(8)));
typedef float floatx4 __attribute__((ext_vector_type(4)));

constexpr int NT = 4096, H = 128, CAP = 64;
constexpr int ROWS = 8;                       // rows per block
constexpr int GRID = 512, BLK = 512, GSTRIDE = GRID * BLK;

// bf16 weight arena element offsets (layer-0 qkv region unused: prep reads f32)
constexpr int OFF_QKV  = 0;                 // 4*384*128
constexpr int OFF_AO   = 196608;            // 4*128*128
constexpr int OFF_F1   = 262144;            // 4*256*128
constexpr int OFF_F2   = 393216;            // 4*128*256
constexpr int OFF_LAT1 = 524288;            // 128*128
constexpr int OFF_B1   = 540672;            // 64*128
constexpr int OFF_LAT2 = 548864;            // 16*128
constexpr int W_TOTAL  = 550912;

__device__ __forceinline__ float bfu(u16 u) { return __uint_as_float(((unsigned)u) << 16); }
__device__ __forceinline__ u16 f2bf(float f) {
  unsigned u = __float_as_uint(f);
  u += 0x7fffu + ((u >> 16) & 1u);          // RNE
  return (u16)(u >> 16);
}
__device__ __forceinline__ void unpack8(uint4 u, float* f) {
  f[0] = __uint_as_float(u.x << 16); f[1] = __uint_as_float(u.x & 0xffff0000u);
  f[2] = __uint_as_float(u.y << 16); f[3] = __uint_as_float(u.y & 0xffff0000u);
  f[4] = __uint_as_float(u.z << 16); f[5] = __uint_as_float(u.z & 0xffff0000u);
  f[6] = __uint_as_float(u.w << 16); f[7] = __uint_as_float(u.w & 0xffff0000u);
}
__device__ __forceinline__ short8_t cvt8(const float* bp) {   // f32 row -> bf16 frag
  const float4 f0 = *(const float4*)bp, f1 = *(const float4*)(bp + 4);
  short8_t r;
  r[0] = (short)f2bf(f0.x); r[1] = (short)f2bf(f0.y);
  r[2] = (short)f2bf(f0.z); r[3] = (short)f2bf(f0.w);
  r[4] = (short)f2bf(f1.x); r[5] = (short)f2bf(f1.y);
  r[6] = (short)f2bf(f1.z); r[7] = (short)f2bf(f1.w);
  return r;
}

// Device-coherent (LLC-level) stores: agent-scope relaxed atomics emit sc0/sc1
// encodings that bypass the non-coherent per-XCD L2. Producers use these for
// ALL cross-block data (W, QKV epochs) so NO wbl2/inv is ever needed
// mid-kernel; consumers read plain-cached (each address is written in exactly
// one epoch and only read in later epochs; L1/L2 invalidated at launch).
__device__ __forceinline__ void st64(unsigned long long* p, unsigned long long v) {
  __hip_atomic_store(p, v, __ATOMIC_RELAXED, __HIP_MEMORY_SCOPE_AGENT);
}
__device__ __forceinline__ void st16(u16* p, u16 v) {
  __hip_atomic_store(p, v, __ATOMIC_RELAXED, __HIP_MEMORY_SCOPE_AGENT);
}

// Grid barrier: monotone counter, thread-0 arrival + agent-scope polling.
// RESIDENCY GUARANTEE (round-4 deadlock fix): __launch_bounds__(512, 4)
// declares 4 waves/EU = 16 waves/CU = 2 x 8-wave blocks per CU, forcing
// VGPR <= 128 (code needs ~76) so the HW genuinely co-schedules 2 blocks/CU.
// GRID=512 = 2 x 256 CUs -> all blocks resident -> spin cannot deadlock.
// (Round 4 used min-waves=2, which only guarantees 1 block/CU and allows
// up to 256 VGPR -> possible 256-resident deadlock.)
__device__ __forceinline__ void gridbar(int* bar, int want) {
  __syncthreads();
  if (threadIdx.x == 0) {
    asm volatile("" ::: "memory");
    __hip_atomic_fetch_add(bar, 1, __ATOMIC_RELAXED, __HIP_MEMORY_SCOPE_AGENT);
    while (__hip_atomic_load(bar, __ATOMIC_RELAXED, __HIP_MEMORY_SCOPE_AGENT) < want)
      __builtin_amdgcn_s_sleep(2);
    asm volatile("" ::: "memory");
  }
  __syncthreads();
}

struct Prm {
  const float *xr, *in_w, *in_b, *ln1_s, *ln1_b, *qkv_w, *qkv_b, *ao_w, *ao_b,
              *ln2_s, *ln2_b, *f1_w, *f1_b, *f2_w, *f2_b, *lat1_w, *lat1_b,
              *lat2_w, *lat2_b, *b1_w, *b1_b, *b2_w, *b2_b;
  u16* W; u16* QKV[4]; int* bar; float* out;
};

// ================== fully fused: prep + 4 layers + heads ==================
// 512 blocks (2/CU co-resident for latency hiding), 8 rows/block.
// MFMA tiles stay 16-row: A-fragment rows 8..15 carry garbage which only
// affects output rows 8..15 -- never written back (row<8 guards).
__global__ __launch_bounds__(BLK, 4) void fused_kernel(Prm p) {
  const int t = threadIdx.x, bid = blockIdx.x;
  const int lane = t & 63, w = t >> 6;
  const int lr = lane & 15, quad = lane >> 4;
  const int gtid = bid * BLK + t;
  const int r0 = bid * ROWS;
  const floatx4 FZ = {0.f, 0.f, 0.f, 0.f};
  int bar_k = 0;

  __shared__ float Xs[ROWS][132];               // persistent across layers
  __shared__ int NIs[ROWS][CAP];                // persistent
  __shared__ int NCs[ROWS];                     // persistent
  __shared__ union {
    unsigned long long words[8][64];
    struct { u16 A16[16][152]; u16 FF1[16][280]; } g;
    u16 QS[ROWS][384];
  } sm;

  auto stage_x = [&](const float* sc, const float* bi, bool do_ln) {
    if (t < ROWS * 32) {
      const int r = t >> 5, j0 = (t & 31) * 4;
      const float4 xv = *(const float4*)&Xs[r][j0];
      float v0 = xv.x, v1 = xv.y, v2 = xv.z, v3 = xv.w;
      if (do_ln) {
        float s = v0 + v1 + v2 + v3;
        float ss = v0 * v0 + v1 * v1 + v2 * v2 + v3 * v3;
#pragma unroll
        for (int off = 1; off <= 16; off <<= 1) {
          s += __shfl_xor(s, off); ss += __shfl_xor(ss, off);
        }
        const float mean = s * (1.f / 128.f);
        const float rstd = rsqrtf(ss * (1.f / 128.f) - mean * mean + 1e-5f);
        v0 = (v0 - mean) * rstd * sc[j0]     + bi[j0];
        v1 = (v1 - mean) * rstd * sc[j0 + 1] + bi[j0 + 1];
        v2 = (v2 - mean) * rstd * sc[j0 + 2] + bi[j0 + 2];
        v3 = (v3 - mean) * rstd * sc[j0 + 3] + bi[j0 + 3];
      }
      uint2 pk;
      pk.x = (unsigned)f2bf(v0) | ((unsigned)f2bf(v1) << 16);
      pk.y = (unsigned)f2bf(v2) | ((unsigned)f2bf(v3) << 16);
      *(uint2*)&sm.g.A16[r][j0] = pk;
    }
  };

  // ======================= prep phase =======================
  // wconv: skip unused layer-0 qkv region (LLC-coherent stores)
  for (int i = 49152 + gtid; i < W_TOTAL; i += GSTRIDE) {
    float v;
    if      (i < OFF_AO)   v = p.qkv_w[i];
    else if (i < OFF_F1)   v = p.ao_w[i - OFF_AO];
    else if (i < OFF_F2)   v = p.f1_w[i - OFF_F1];
    else if (i < OFF_LAT1) v = p.f2_w[i - OFF_F2];
    else if (i < OFF_B1)   v = p.lat1_w[i - OFF_LAT1];
    else if (i < OFF_LAT2) v = p.b1_w[i - OFF_B1];
    else                   v = p.lat2_w[i - OFF_LAT2];
    st16(&p.W[i], f2bf(v));
  }
  // in_proj for own 8 rows -> Xs
  for (int i = t; i < ROWS * H; i += BLK) {
    const int r = i >> 7, c = i & 127;
    const float* xp = p.xr + (size_t)(r0 + r) * 16;
    const float* wp = p.in_w + c * 16;
    float acc = p.in_b[c];
#pragma unroll
    for (int k = 0; k < 16; ++k) acc += xp[k] * wp[k];
    Xs[r][c] = acc;
  }
  // neighbor lists for own 8 rows -> LDS NIs/NCs (persist across layers)
  {
    double qe[8], qp_[8];
#pragma unroll
    for (int j = 0; j < 8; ++j) {
      qe[j]  = (double)p.xr[(r0 + j) * 16 + 1] * 5.24 - 2.62;
      qp_[j] = (double)p.xr[(r0 + j) * 16 + 2] * 6.2832 - 3.1416;
    }
    for (int c = 0; c < 8; ++c) {
      const int k = c * 512 + t;
      const double ke = (double)p.xr[k * 16 + 1] * 5.24 - 2.62;
      const double kp = (double)p.xr[k * 16 + 2] * 6.2832 - 3.1416;
#pragma unroll
      for (int j = 0; j < 8; ++j) {
        const double de = qe[j] - ke;
        double dp = qp_[j] - kp;
        dp -= 6.283185307179586 * rint(dp * 0.15915494309189535);  // atan2 wrap
        const unsigned long long bm = __ballot((de * de + dp * dp) <= 0.04);
        if (lane == 0) sm.words[j][c * 8 + w] = bm;
      }
    }
    __syncthreads();
    {
      unsigned long long m = sm.words[w][lane];
      const int cnt = __popcll(m);
      int incl = cnt;
#pragma unroll
      for (int off = 1; off < 64; off <<= 1) {
        const int n = __shfl_up(incl, off);
        if (lane >= off) incl += n;
      }
      int pos = incl - cnt;
      const int kbase = (lane >> 3) * 512 + (lane & 7) * 64;
      while (m) {
        const int b = __builtin_ctzll(m);
        m &= m - 1;
        if (pos < CAP) NIs[w][pos] = kbase + b;
        ++pos;
      }
      if (lane == 63) NCs[w] = incl > CAP ? CAP : incl;
    }
    __syncthreads();
  }
  // LN1(0) -> A16
  stage_x(p.ln1_s, p.ln1_b, true);
  __syncthreads();
  // qkv0 from f32 weights
  {
    const int c0 = w * 48;
    floatx4 a0 = FZ, a1 = FZ, a2 = FZ;
#pragma unroll
    for (int k0 = 0; k0 < 128; k0 += 32) {
      short8_t a  = *(const short8_t*)&sm.g.A16[lr][k0 + quad * 8];
      short8_t b0 = cvt8(&p.qkv_w[(size_t)(c0 + lr) * 128 + k0 + quad * 8]);
      short8_t b1 = cvt8(&p.qkv_w[(size_t)(c0 + 16 + lr) * 128 + k0 + quad * 8]);
      short8_t b2 = cvt8(&p.qkv_w[(size_t)(c0 + 32 + lr) * 128 + k0 + quad * 8]);
      a0 = __builtin_amdgcn_mfma_f32_16x16x32_bf16(a, b0, a0, 0, 0, 0);
      a1 = __builtin_amdgcn_mfma_f32_16x16x32_bf16(a, b1, a1, 0, 0, 0);
      a2 = __builtin_amdgcn_mfma_f32_16x16x32_bf16(a, b2, a2, 0, 0, 0);
    }
    __syncthreads();
#pragma unroll
    for (int r = 0; r < 4; ++r) {
      const int row = quad * 4 + r;
      if (row < ROWS) {
        sm.QS[row][c0 + lr]      = f2bf(a0[r] + p.qkv_b[c0 + lr]);
        sm.QS[row][c0 + 16 + lr] = f2bf(a1[r] + p.qkv_b[c0 + 16 + lr]);
        sm.QS[row][c0 + 32 + lr] = f2bf(a2[r] + p.qkv_b[c0 + 32 + lr]);
      }
    }
    __syncthreads();
    unsigned long long* d64 = (unsigned long long*)(p.QKV[0] + (size_t)r0 * 384);
    const unsigned long long* s64 = (const unsigned long long*)&sm.QS[0][0];
    for (int j = t; j < ROWS * 96; j += BLK) st64(&d64[j], s64[j]);
  }
  gridbar(p.bar, GRID * ++bar_k);   // QKV[0] + W visible to all blocks

  // ======================= layer loop =======================
  for (int l = 0; l < 4; ++l) {
    const u16* __restrict__ qsrc = p.QKV[l];
    u16* __restrict__ qdst = (l < 3) ? p.QKV[l + 1] : nullptr;

    // --- attention: 64 (q,h) pairs, 8 threads/pair over neighbors ---
    {
      const int pr = t >> 3, sub = t & 7;
      const int lq = pr >> 3, h = pr & 7;
      const u16* qp = qsrc + (size_t)(r0 + lq) * 384 + h * 16;
      float qv[16];
      { uint4 a = *(const uint4*)qp, b = *(const uint4*)(qp + 8);
        unpack8(a, qv); unpack8(b, qv + 8); }
#pragma unroll
      for (int d = 0; d < 16; ++d) qv[d] *= 0.25f;        // 1/sqrt(HD)
      float o[16];
#pragma unroll
      for (int d = 0; d < 16; ++d) o[d] = 0.f;
      float se = 0.f;
      const int cnt = NCs[lq];
      for (int i = sub; i < cnt; i += 8) {
        const int nb = NIs[lq][i];
        const u16* kp = qsrc + (size_t)nb * 384 + 128 + h * 16;
        float kv[16], vv[16];
        { uint4 a = *(const uint4*)kp;         uint4 b = *(const uint4*)(kp + 8);
          unpack8(a, kv); unpack8(b, kv + 8); }
        { uint4 a = *(const uint4*)(kp + 128); uint4 b = *(const uint4*)(kp + 136);
          unpack8(a, vv); unpack8(b, vv + 8); }
        float s0 = 0.f, s1 = 0.f, s2 = 0.f, s3 = 0.f;
#pragma unroll
        for (int d = 0; d < 16; d += 4) {
          s0 += qv[d] * kv[d];         s1 += qv[d + 1] * kv[d + 1];
          s2 += qv[d + 2] * kv[d + 2]; s3 += qv[d + 3] * kv[d + 3];
        }
        const float e = __expf((s0 + s1) + (s2 + s3));    // |s|<~0.5, no max-sub
        se += e;
#pragma unroll
        for (int d = 0; d < 16; ++d) o[d] += e * vv[d];
      }
#pragma unroll
      for (int off = 1; off < 8; off <<= 1) {
#pragma unroll
        for (int d = 0; d < 16; ++d) o[d] += __shfl_xor(o[d], off);
        se += __shfl_xor(se, off);
      }
      if (sub == 0) {
        const float inv = 1.f / se;
        uint4 w0, w1;
        w0.x = (unsigned)f2bf(o[0] * inv)  | ((unsigned)f2bf(o[1] * inv) << 16);
        w0.y = (unsigned)f2bf(o[2] * inv)  | ((unsigned)f2bf(o[3] * inv) << 16);
        w0.z = (unsigned)f2bf(o[4] * inv)  | ((unsigned)f2bf(o[5] * inv) << 16);
        w0.w = (unsigned)f2bf(o[6] * inv)  | ((unsigned)f2bf(o[7] * inv) << 16);
        w1.x = (unsigned)f2bf(o[8] * inv)  | ((unsigned)f2bf(o[9] * inv) << 16);
        w1.y = (unsigned)f2bf(o[10] * inv) | ((unsigned)f2bf(o[11] * inv) << 16);
        w1.z = (unsigned)f2bf(o[12] * inv) | ((unsigned)f2bf(o[13] * inv) << 16);
        w1.w = (unsigned)f2bf(o[14] * inv) | ((unsigned)f2bf(o[15] * inv) << 16);
        *(uint4*)&sm.g.A16[lq][h * 16]     = w0;
        *(uint4*)&sm.g.A16[lq][h * 16 + 8] = w1;
      }
    }
    __syncthreads();
    // --- ao GEMM + residual ---
    {
      const u16* Bw = p.W + OFF_AO + l * 16384;
      const float* ab = p.ao_b + l * 128;
      const int col = w * 16 + lr;
      floatx4 acc = FZ;
#pragma unroll
      for (int k0 = 0; k0 < 128; k0 += 32) {
        short8_t a = *(const short8_t*)&sm.g.A16[lr][k0 + quad * 8];
        short8_t b = *(const short8_t*)&Bw[(size_t)col * 128 + k0 + quad * 8];
        acc = __builtin_amdgcn_mfma_f32_16x16x32_bf16(a, b, acc, 0, 0, 0);
      }
      const float bv = ab[col];
#pragma unroll
      for (int r = 0; r < 4; ++r) {
        const int row = quad * 4 + r;
        if (row < ROWS) Xs[row][col] += acc[r] + bv;
      }
    }
    __syncthreads();
    // --- LN2 -> f1 (relu) -> FF1 ---
    stage_x(p.ln2_s + l * 128, p.ln2_b + l * 128, true);
    __syncthreads();
    {
      const u16* Bw = p.W + OFF_F1 + l * 32768;
      const float* fb = p.f1_b + l * 256;
      const int c0 = w * 32;
      floatx4 a0 = FZ, a1 = FZ;
#pragma unroll
      for (int k0 = 0; k0 < 128; k0 += 32) {
        short8_t a  = *(const short8_t*)&sm.g.A16[lr][k0 + quad * 8];
        short8_t b0 = *(const short8_t*)&Bw[(size_t)(c0 + lr) * 128 + k0 + quad * 8];
        short8_t b1 = *(const short8_t*)&Bw[(size_t)(c0 + 16 + lr) * 128 + k0 + quad * 8];
        a0 = __builtin_amdgcn_mfma_f32_16x16x32_bf16(a, b0, a0, 0, 0, 0);
        a1 = __builtin_amdgcn_mfma_f32_16x16x32_bf16(a, b1, a1, 0, 0, 0);
      }
#pragma unroll
      for (int r = 0; r < 4; ++r) {
        const int row = quad * 4 + r;
        if (row < ROWS) {
          sm.g.FF1[row][c0 + lr]      = f2bf(fmaxf(a0[r] + fb[c0 + lr], 0.f));
          sm.g.FF1[row][c0 + 16 + lr] = f2bf(fmaxf(a1[r] + fb[c0 + 16 + lr], 0.f));
        }
      }
    }
    __syncthreads();
    // --- f2 + residual ---
    {
      const u16* Bw = p.W + OFF_F2 + l * 32768;
      const float* fb = p.f2_b + l * 128;
      const int col = w * 16 + lr;
      floatx4 acc = FZ;
#pragma unroll
      for (int k0 = 0; k0 < 256; k0 += 32) {
        short8_t a = *(const short8_t*)&sm.g.FF1[lr][k0 + quad * 8];
        short8_t b = *(const short8_t*)&Bw[(size_t)col * 256 + k0 + quad * 8];
        acc = __builtin_amdgcn_mfma_f32_16x16x32_bf16(a, b, acc, 0, 0, 0);
      }
      const float bv = fb[col];
#pragma unroll
      for (int r = 0; r < 4; ++r) {
        const int row = quad * 4 + r;
        if (row < ROWS) Xs[row][col] += acc[r] + bv;
      }
    }
    __syncthreads();
    if (l < 3) {
      // LN1(l+1) + qkv(l+1) -> qdst; Xs stays resident in LDS
      stage_x(p.ln1_s + (l + 1) * 128, p.ln1_b + (l + 1) * 128, true);
      __syncthreads();
      {
        const u16* Bw = p.W + OFF_QKV + (l + 1) * 49152;
        const float* qb = p.qkv_b + (l + 1) * 384;
        const int c0 = w * 48;
        floatx4 a0 = FZ, a1 = FZ, a2 = FZ;
#pragma unroll
        for (int k0 = 0; k0 < 128; k0 += 32) {
          short8_t a  = *(const short8_t*)&sm.g.A16[lr][k0 + quad * 8];
          short8_t b0 = *(const short8_t*)&Bw[(size_t)(c0 + lr) * 128 + k0 + quad * 8];
          short8_t b1 = *(const short8_t*)&Bw[(size_t)(c0 + 16 + lr) * 128 + k0 + quad * 8];
          short8_t b2 = *(const short8_t*)&Bw[(size_t)(c0 + 32 + lr) * 128 + k0 + quad * 8];
          a0 = __builtin_amdgcn_mfma_f32_16x16x32_bf16(a, b0, a0, 0, 0, 0);
          a1 = __builtin_amdgcn_mfma_f32_16x16x32_bf16(a, b1, a1, 0, 0, 0);
          a2 = __builtin_amdgcn_mfma_f32_16x16x32_bf16(a, b2, a2, 0, 0, 0);
        }
        __syncthreads();
#pragma unroll
        for (int r = 0; r < 4; ++r) {
          const int row = quad * 4 + r;
          if (row < ROWS) {
            sm.QS[row][c0 + lr]      = f2bf(a0[r] + qb[c0 + lr]);
            sm.QS[row][c0 + 16 + lr] = f2bf(a1[r] + qb[c0 + 16 + lr]);
            sm.QS[row][c0 + 32 + lr] = f2bf(a2[r] + qb[c0 + 32 + lr]);
          }
        }
        __syncthreads();
        unsigned long long* d64 = (unsigned long long*)(qdst + (size_t)r0 * 384);
        const unsigned long long* s64 = (const unsigned long long*)&sm.QS[0][0];
        for (int j = t; j < ROWS * 96; j += BLK) st64(&d64[j], s64[j]);
      }
      gridbar(p.bar, GRID * ++bar_k);   // next layer's attention gathers arbitrary rows
    } else {
      // --- heads: [lat1|b1] (N=192) -> lat2+normalize, beta ---
      stage_x(nullptr, nullptr, false);
      __syncthreads();
      {
        const int c0 = w * 32;
        if (c0 < 192) {
          const u16* Bw = p.W + OFF_LAT1;
          floatx4 a0 = FZ, a1 = FZ;
#pragma unroll
          for (int k0 = 0; k0 < 128; k0 += 32) {
            short8_t a  = *(const short8_t*)&sm.g.A16[lr][k0 + quad * 8];
            short8_t b0 = *(const short8_t*)&Bw[(size_t)(c0 + lr) * 128 + k0 + quad * 8];
            short8_t b1 = *(const short8_t*)&Bw[(size_t)(c0 + 16 + lr) * 128 + k0 + quad * 8];
            a0 = __builtin_amdgcn_mfma_f32_16x16x32_bf16(a, b0, a0, 0, 0, 0);
            a1 = __builtin_amdgcn_mfma_f32_16x16x32_bf16(a, b1, a1, 0, 0, 0);
          }
          const int cA = c0 + lr, cB = c0 + 16 + lr;
          const float bA = cA < 128 ? p.lat1_b[cA] : p.b1_b[cA - 128];
          const float bB = cB < 128 ? p.lat1_b[cB] : p.b1_b[cB - 128];
#pragma unroll
          for (int r = 0; r < 4; ++r) {
            const int row = quad * 4 + r;
            if (row < ROWS) {
              sm.g.FF1[row][cA] = f2bf(fmaxf(a0[r] + bA, 0.f));
              sm.g.FF1[row][cB] = f2bf(fmaxf(a1[r] + bB, 0.f));
            }
          }
        }
      }
      __syncthreads();
      if (t < ROWS * 16) {
        const int r = t >> 4, c = t & 15;
        float acc = p.lat2_b[c];
        const u16* gw = p.W + OFF_LAT2 + c * 128;
        for (int k = 0; k < 128; ++k) acc += bfu(sm.g.FF1[r][k]) * bfu(gw[k]);
        float ss = acc * acc;
        ss += __shfl_xor(ss, 1); ss += __shfl_xor(ss, 2);
        ss += __shfl_xor(ss, 4); ss += __shfl_xor(ss, 8);
        p.out[NT + (size_t)(r0 + r) * 16 + c] = acc / fmaxf(sqrtf(ss), 1e-12f);
        float v = 0.f;
#pragma unroll
        for (int i = 0; i < 4; ++i)
          v += bfu(sm.g.FF1[r][128 + c * 4 + i]) * p.b2_w[c * 4 + i];
        v += __shfl_xor(v, 1); v += __shfl_xor(v, 2);
        v += __shfl_xor(v, 4); v += __shfl_xor(v, 8);
        if (c == 0) {
          v += p.b2_b[0];
          const float beta = 1.f / (1.f + __expf(-v));
          p.out[r0 + r] = fminf(fmaxf(beta, 1e-6f), 1.f - 1e-6f);
        }
      }
    }
  }
}

extern "C" void kernel_launch(void* const* d_in, const int* in_sizes, int n_in,
                              void* d_out, int out_size, void* d_ws, size_t ws_size,
                              hipStream_t stream) {
  Prm prm;
  prm.xr    = (const float*)d_in[0];
  prm.in_w  = (const float*)d_in[2];  prm.in_b  = (const float*)d_in[3];
  prm.ln1_s = (const float*)d_in[4];  prm.ln1_b = (const float*)d_in[5];
  prm.qkv_w = (const float*)d_in[6];  prm.qkv_b = (const float*)d_in[7];
  prm.ao_w  = (const float*)d_in[8];  prm.ao_b  = (const float*)d_in[9];
  prm.ln2_s = (const float*)d_in[10]; prm.ln2_b = (const float*)d_in[11];
  prm.f1_w  = (const float*)d_in[12]; prm.f1_b  = (const float*)d_in[13];
  prm.f2_w  = (const float*)d_in[14]; prm.f2_b  = (const float*)d_in[15];
  prm.lat1_w= (const float*)d_in[16]; prm.lat1_b= (const float*)d_in[17];
  prm.lat2_w= (const float*)d_in[18]; prm.lat2_b= (const float*)d_in[19];
  prm.b1_w  = (const float*)d_in[20]; prm.b1_b  = (const float*)d_in[21];
  prm.b2_w  = (const float*)d_in[22]; prm.b2_b  = (const float*)d_in[23];
  prm.out   = (float*)d_out;

  char* pw = (char*)d_ws;
  prm.W    = (u16*)pw;   pw += ((size_t)W_TOTAL * 2 + 255) & ~(size_t)255;
  for (int i = 0; i < 4; ++i) { prm.QKV[i] = (u16*)pw; pw += (size_t)NT * 384 * 2; }
  prm.bar  = (int*)pw;   pw += 256;

  hipMemsetAsync(prm.bar, 0, 256, stream);
  fused_kernel<<<GRID, BLK, 0, stream>>>(prm);
}

// Round 6
// 192.702 us; speedup vs baseline: 1.6420x; 1.6420x over previous
//
#include <hip/hip_runtime.h>
#include <hip/hip_bf16.h>

typedef unsigned short u16;
typedef short short8_t __attribute__((ext_vector_type(8)));
typedef float floatx4 __attribute__((ext_vector_type(4)));

constexpr int NT = 4096, H = 128, CAP = 64;
constexpr int GRID = 256, BLK = 512, GSTRIDE = GRID * BLK;
constexpr int NGRP = 8, GRPSZ = GRID / NGRP;   // two-level barrier groups

// bf16 weight arena element offsets (layer-0 qkv region unused: prep reads f32)
constexpr int OFF_QKV  = 0;                 // 4*384*128
constexpr int OFF_AO   = 196608;            // 4*128*128
constexpr int OFF_F1   = 262144;            // 4*256*128
constexpr int OFF_F2   = 393216;            // 4*128*256
constexpr int OFF_LAT1 = 524288;            // 128*128
constexpr int OFF_B1   = 540672;            // 64*128
constexpr int OFF_LAT2 = 548864;            // 16*128
constexpr int W_TOTAL  = 550912;

__device__ __forceinline__ float bfu(u16 u) { return __uint_as_float(((unsigned)u) << 16); }
__device__ __forceinline__ u16 f2bf(float f) {
  unsigned u = __float_as_uint(f);
  u += 0x7fffu + ((u >> 16) & 1u);          // RNE
  return (u16)(u >> 16);
}
__device__ __forceinline__ void unpack8(uint4 u, float* f) {
  f[0] = __uint_as_float(u.x << 16); f[1] = __uint_as_float(u.x & 0xffff0000u);
  f[2] = __uint_as_float(u.y << 16); f[3] = __uint_as_float(u.y & 0xffff0000u);
  f[4] = __uint_as_float(u.z << 16); f[5] = __uint_as_float(u.z & 0xffff0000u);
  f[6] = __uint_as_float(u.w << 16); f[7] = __uint_as_float(u.w & 0xffff0000u);
}
__device__ __forceinline__ short8_t cvt8(const float* bp) {   // f32 row -> bf16 frag
  const float4 f0 = *(const float4*)bp, f1 = *(const float4*)(bp + 4);
  short8_t r;
  r[0] = (short)f2bf(f0.x); r[1] = (short)f2bf(f0.y);
  r[2] = (short)f2bf(f0.z); r[3] = (short)f2bf(f0.w);
  r[4] = (short)f2bf(f1.x); r[5] = (short)f2bf(f1.y);
  r[6] = (short)f2bf(f1.z); r[7] = (short)f2bf(f1.w);
  return r;
}

// Device-coherent (LLC-level) stores: agent-scope relaxed atomics emit sc0/sc1
// encodings that bypass the non-coherent per-XCD L2. Producers use these for
// ALL cross-block data (W, QKV epochs) so NO wbl2/inv is ever needed
// mid-kernel; consumers read plain-cached (each address is written in exactly
// one epoch and only read in later epochs; L1/L2 invalidated at launch).
__device__ __forceinline__ void st64(unsigned long long* p, unsigned long long v) {
  __hip_atomic_store(p, v, __ATOMIC_RELAXED, __HIP_MEMORY_SCOPE_AGENT);
}
__device__ __forceinline__ void st16(u16* p, u16 v) {
  __hip_atomic_store(p, v, __ATOMIC_RELAXED, __HIP_MEMORY_SCOPE_AGENT);
}

// Two-level grid barrier (round-6 change): flat 256-way same-line atomic
// contention -> 8 group lines (32 arrivals each, 64B apart) + 1 root line
// (8 leader arrivals). Monotone counters, no reset. Epoch e complete when
// root == NGRP*e. Same visibility argument as the flat barrier that passed
// rounds 2-3: __syncthreads drains vmcnt(0) (compiler-guaranteed) before
// arrival, sc0/sc1 store retirement == LLC visibility.
// Residency: GRID=256 at __launch_bounds__(512,2) -> >=1 block/CU x 256 CU,
// all blocks resident -> spin cannot deadlock.
__device__ __forceinline__ void gridbar(int* bar, int grp, int e) {
  __syncthreads();
  if (threadIdx.x == 0) {
    asm volatile("" ::: "memory");
    int* root = bar;
    int* gcnt = bar + 16 + 16 * grp;          // 64B-separated lines
    const int old = __hip_atomic_fetch_add(gcnt, 1, __ATOMIC_RELAXED,
                                           __HIP_MEMORY_SCOPE_AGENT);
    if (old == GRPSZ * e - 1)                 // last arrival of this group
      __hip_atomic_fetch_add(root, 1, __ATOMIC_RELAXED, __HIP_MEMORY_SCOPE_AGENT);
    while (__hip_atomic_load(root, __ATOMIC_RELAXED, __HIP_MEMORY_SCOPE_AGENT) < NGRP * e)
      __builtin_amdgcn_s_sleep(2);
    asm volatile("" ::: "memory");
  }
  __syncthreads();
}

struct Prm {
  const float *xr, *in_w, *in_b, *ln1_s, *ln1_b, *qkv_w, *qkv_b, *ao_w, *ao_b,
              *ln2_s, *ln2_b, *f1_w, *f1_b, *f2_w, *f2_b, *lat1_w, *lat1_b,
              *lat2_w, *lat2_b, *b1_w, *b1_b, *b2_w, *b2_b;
  u16* W; u16* QKV[4]; int* bar; float* out;
};

// ================== fully fused: prep + 4 layers + heads ==================
// Round-3 structure (known 107us, VGPR 76, no spills): 256 blocks x 512thr,
// 16 rows/block, 1 block/CU. Round-5's 8-row/2-block config regressed 2.2x
// (launch_bounds(512,4) -> 64 VGPR -> attention spills, +4MB scratch writes).
__global__ __launch_bounds__(BLK, 2) void fused_kernel(Prm p) {
  const int t = threadIdx.x, bid = blockIdx.x;
  const int lane = t & 63, w = t >> 6;
  const int lr = lane & 15, quad = lane >> 4;
  const int gtid = bid * BLK + t;
  const int r0 = bid * 16;
  const int grp = bid >> 5;                   // 8 groups of 32 blocks
  const floatx4 FZ = {0.f, 0.f, 0.f, 0.f};
  int bar_k = 0;

  __shared__ float Xs[16][132];                 // persistent across layers
  __shared__ int NIs[16][CAP];                  // persistent
  __shared__ int NCs[16];                       // persistent
  __shared__ union {
    unsigned long long words[8][64];
    struct { u16 A16[16][152]; u16 FF1[16][280]; } g;
    u16 QS[16][384];
  } sm;

  auto stage_x = [&](const float* sc, const float* bi, bool do_ln) {
    const int r = t >> 5, j0 = (t & 31) * 4;
    const float4 xv = *(const float4*)&Xs[r][j0];
    float v0 = xv.x, v1 = xv.y, v2 = xv.z, v3 = xv.w;
    if (do_ln) {
      float s = v0 + v1 + v2 + v3;
      float ss = v0 * v0 + v1 * v1 + v2 * v2 + v3 * v3;
#pragma unroll
      for (int off = 1; off <= 16; off <<= 1) {
        s += __shfl_xor(s, off); ss += __shfl_xor(ss, off);
      }
      const float mean = s * (1.f / 128.f);
      const float rstd = rsqrtf(ss * (1.f / 128.f) - mean * mean + 1e-5f);
      v0 = (v0 - mean) * rstd * sc[j0]     + bi[j0];
      v1 = (v1 - mean) * rstd * sc[j0 + 1] + bi[j0 + 1];
      v2 = (v2 - mean) * rstd * sc[j0 + 2] + bi[j0 + 2];
      v3 = (v3 - mean) * rstd * sc[j0 + 3] + bi[j0 + 3];
    }
    uint2 pk;
    pk.x = (unsigned)f2bf(v0) | ((unsigned)f2bf(v1) << 16);
    pk.y = (unsigned)f2bf(v2) | ((unsigned)f2bf(v3) << 16);
    *(uint2*)&sm.g.A16[r][j0] = pk;
  };

  // ======================= prep phase =======================
  // wconv: skip unused layer-0 qkv region (LLC-coherent stores)
  for (int i = 49152 + gtid; i < W_TOTAL; i += GSTRIDE) {
    float v;
    if      (i < OFF_AO)   v = p.qkv_w[i];
    else if (i < OFF_F1)   v = p.ao_w[i - OFF_AO];
    else if (i < OFF_F2)   v = p.f1_w[i - OFF_F1];
    else if (i < OFF_LAT1) v = p.f2_w[i - OFF_F2];
    else if (i < OFF_B1)   v = p.lat1_w[i - OFF_LAT1];
    else if (i < OFF_LAT2) v = p.b1_w[i - OFF_B1];
    else                   v = p.lat2_w[i - OFF_LAT2];
    st16(&p.W[i], f2bf(v));
  }
  // in_proj for own 16 rows -> Xs (LDS only; no global X round-trip)
  for (int i = t; i < 16 * H; i += BLK) {
    const int r = i >> 7, c = i & 127;
    const float* xp = p.xr + (size_t)(r0 + r) * 16;
    const float* wp = p.in_w + c * 16;
    float acc = p.in_b[c];
#pragma unroll
    for (int k = 0; k < 16; ++k) acc += xp[k] * wp[k];
    Xs[r][c] = acc;
  }
  // neighbor lists for own 16 rows -> LDS NIs/NCs (persist across layers)
  for (int uu = 0; uu < 2; ++uu) {
    const int q0 = r0 + uu * 8;
    double qe[8], qp_[8];
#pragma unroll
    for (int j = 0; j < 8; ++j) {
      qe[j]  = (double)p.xr[(q0 + j) * 16 + 1] * 5.24 - 2.62;
      qp_[j] = (double)p.xr[(q0 + j) * 16 + 2] * 6.2832 - 3.1416;
    }
    for (int c = 0; c < 8; ++c) {
      const int k = c * 512 + t;
      const double ke = (double)p.xr[k * 16 + 1] * 5.24 - 2.62;
      const double kp = (double)p.xr[k * 16 + 2] * 6.2832 - 3.1416;
#pragma unroll
      for (int j = 0; j < 8; ++j) {
        const double de = qe[j] - ke;
        double dp = qp_[j] - kp;
        dp -= 6.283185307179586 * rint(dp * 0.15915494309189535);  // atan2 wrap
        const unsigned long long bm = __ballot((de * de + dp * dp) <= 0.04);
        if (lane == 0) sm.words[j][c * 8 + w] = bm;
      }
    }
    __syncthreads();
    {
      unsigned long long m = sm.words[w][lane];
      const int cnt = __popcll(m);
      int incl = cnt;
#pragma unroll
      for (int off = 1; off < 64; off <<= 1) {
        const int n = __shfl_up(incl, off);
        if (lane >= off) incl += n;
      }
      int pos = incl - cnt;
      const int lq = uu * 8 + w;
      const int kbase = (lane >> 3) * 512 + (lane & 7) * 64;
      while (m) {
        const int b = __builtin_ctzll(m);
        m &= m - 1;
        if (pos < CAP) NIs[lq][pos] = kbase + b;
        ++pos;
      }
      if (lane == 63) NCs[lq] = incl > CAP ? CAP : incl;
    }
    __syncthreads();
  }
  // LN1(0) -> A16
  stage_x(p.ln1_s, p.ln1_b, true);
  __syncthreads();
  // qkv0 from f32 weights
  {
    const int c0 = w * 48;
    floatx4 a0 = FZ, a1 = FZ, a2 = FZ;
#pragma unroll
    for (int k0 = 0; k0 < 128; k0 += 32) {
      short8_t a  = *(const short8_t*)&sm.g.A16[lr][k0 + quad * 8];
      short8_t b0 = cvt8(&p.qkv_w[(size_t)(c0 + lr) * 128 + k0 + quad * 8]);
      short8_t b1 = cvt8(&p.qkv_w[(size_t)(c0 + 16 + lr) * 128 + k0 + quad * 8]);
      short8_t b2 = cvt8(&p.qkv_w[(size_t)(c0 + 32 + lr) * 128 + k0 + quad * 8]);
      a0 = __builtin_amdgcn_mfma_f32_16x16x32_bf16(a, b0, a0, 0, 0, 0);
      a1 = __builtin_amdgcn_mfma_f32_16x16x32_bf16(a, b1, a1, 0, 0, 0);
      a2 = __builtin_amdgcn_mfma_f32_16x16x32_bf16(a, b2, a2, 0, 0, 0);
    }
    __syncthreads();
#pragma unroll
    for (int r = 0; r < 4; ++r) {
      const int row = quad * 4 + r;
      sm.QS[row][c0 + lr]      = f2bf(a0[r] + p.qkv_b[c0 + lr]);
      sm.QS[row][c0 + 16 + lr] = f2bf(a1[r] + p.qkv_b[c0 + 16 + lr]);
      sm.QS[row][c0 + 32 + lr] = f2bf(a2[r] + p.qkv_b[c0 + 32 + lr]);
    }
    __syncthreads();
    unsigned long long* d64 = (unsigned long long*)(p.QKV[0] + (size_t)r0 * 384);
    const unsigned long long* s64 = (const unsigned long long*)&sm.QS[0][0];
    for (int j = t; j < 1536; j += BLK) st64(&d64[j], s64[j]);
  }
  gridbar(p.bar, grp, ++bar_k);   // QKV[0] + W visible to all blocks

  // ======================= layer loop =======================
  for (int l = 0; l < 4; ++l) {
    const u16* __restrict__ qsrc = p.QKV[l];
    u16* __restrict__ qdst = (l < 3) ? p.QKV[l + 1] : nullptr;

    // --- attention: 128 (q,h) pairs, 4 threads/pair over neighbors ---
    {
      const int pr = t >> 2, sub = t & 3;
      const int lq = pr >> 3, h = pr & 7;
      const u16* qp = qsrc + (size_t)(r0 + lq) * 384 + h * 16;
      float qv[16];
      { uint4 a = *(const uint4*)qp, b = *(const uint4*)(qp + 8);
        unpack8(a, qv); unpack8(b, qv + 8); }
#pragma unroll
      for (int d = 0; d < 16; ++d) qv[d] *= 0.25f;        // 1/sqrt(HD)
      float o[16];
#pragma unroll
      for (int d = 0; d < 16; ++d) o[d] = 0.f;
      float se = 0.f;
      const int cnt = NCs[lq];
      for (int i = sub; i < cnt; i += 4) {
        const int nb = NIs[lq][i];
        const u16* kp = qsrc + (size_t)nb * 384 + 128 + h * 16;
        float kv[16], vv[16];
        { uint4 a = *(const uint4*)kp;         uint4 b = *(const uint4*)(kp + 8);
          unpack8(a, kv); unpack8(b, kv + 8); }
        { uint4 a = *(const uint4*)(kp + 128); uint4 b = *(const uint4*)(kp + 136);
          unpack8(a, vv); unpack8(b, vv + 8); }
        float s0 = 0.f, s1 = 0.f, s2 = 0.f, s3 = 0.f;
#pragma unroll
        for (int d = 0; d < 16; d += 4) {
          s0 += qv[d] * kv[d];         s1 += qv[d + 1] * kv[d + 1];
          s2 += qv[d + 2] * kv[d + 2]; s3 += qv[d + 3] * kv[d + 3];
        }
        const float e = __expf((s0 + s1) + (s2 + s3));    // |s|<~0.5, no max-sub
        se += e;
#pragma unroll
        for (int d = 0; d < 16; ++d) o[d] += e * vv[d];
      }
#pragma unroll
      for (int d = 0; d < 16; ++d) o[d] += __shfl_xor(o[d], 1);
      se += __shfl_xor(se, 1);
#pragma unroll
      for (int d = 0; d < 16; ++d) o[d] += __shfl_xor(o[d], 2);
      se += __shfl_xor(se, 2);
      if (sub == 0) {
        const float inv = 1.f / se;
        uint4 w0, w1;
        w0.x = (unsigned)f2bf(o[0] * inv)  | ((unsigned)f2bf(o[1] * inv) << 16);
        w0.y = (unsigned)f2bf(o[2] * inv)  | ((unsigned)f2bf(o[3] * inv) << 16);
        w0.z = (unsigned)f2bf(o[4] * inv)  | ((unsigned)f2bf(o[5] * inv) << 16);
        w0.w = (unsigned)f2bf(o[6] * inv)  | ((unsigned)f2bf(o[7] * inv) << 16);
        w1.x = (unsigned)f2bf(o[8] * inv)  | ((unsigned)f2bf(o[9] * inv) << 16);
        w1.y = (unsigned)f2bf(o[10] * inv) | ((unsigned)f2bf(o[11] * inv) << 16);
        w1.z = (unsigned)f2bf(o[12] * inv) | ((unsigned)f2bf(o[13] * inv) << 16);
        w1.w = (unsigned)f2bf(o[14] * inv) | ((unsigned)f2bf(o[15] * inv) << 16);
        *(uint4*)&sm.g.A16[lq][h * 16]     = w0;
        *(uint4*)&sm.g.A16[lq][h * 16 + 8] = w1;
      }
    }
    __syncthreads();
    // --- ao GEMM + residual ---
    {
      const u16* Bw = p.W + OFF_AO + l * 16384;
      const float* ab = p.ao_b + l * 128;
      const int col = w * 16 + lr;
      floatx4 acc = FZ;
#pragma unroll
      for (int k0 = 0; k0 < 128; k0 += 32) {
        short8_t a = *(const short8_t*)&sm.g.A16[lr][k0 + quad * 8];
        short8_t b = *(const short8_t*)&Bw[(size_t)col * 128 + k0 + quad * 8];
        acc = __builtin_amdgcn_mfma_f32_16x16x32_bf16(a, b, acc, 0, 0, 0);
      }
      const float bv = ab[col];
#pragma unroll
      for (int r = 0; r < 4; ++r)
        Xs[quad * 4 + r][col] += acc[r] + bv;
    }
    __syncthreads();
    // --- LN2 -> f1 (relu) -> FF1 ---
    stage_x(p.ln2_s + l * 128, p.ln2_b + l * 128, true);
    __syncthreads();
    {
      const u16* Bw = p.W + OFF_F1 + l * 32768;
      const float* fb = p.f1_b + l * 256;
      const int c0 = w * 32;
      floatx4 a0 = FZ, a1 = FZ;
#pragma unroll
      for (int k0 = 0; k0 < 128; k0 += 32) {
        short8_t a  = *(const short8_t*)&sm.g.A16[lr][k0 + quad * 8];
        short8_t b0 = *(const short8_t*)&Bw[(size_t)(c0 + lr) * 128 + k0 + quad * 8];
        short8_t b1 = *(const short8_t*)&Bw[(size_t)(c0 + 16 + lr) * 128 + k0 + quad * 8];
        a0 = __builtin_amdgcn_mfma_f32_16x16x32_bf16(a, b0, a0, 0, 0, 0);
        a1 = __builtin_amdgcn_mfma_f32_16x16x32_bf16(a, b1, a1, 0, 0, 0);
      }
#pragma unroll
      for (int r = 0; r < 4; ++r) {
        const int row = quad * 4 + r;
        sm.g.FF1[row][c0 + lr]      = f2bf(fmaxf(a0[r] + fb[c0 + lr], 0.f));
        sm.g.FF1[row][c0 + 16 + lr] = f2bf(fmaxf(a1[r] + fb[c0 + 16 + lr], 0.f));
      }
    }
    __syncthreads();
    // --- f2 + residual ---
    {
      const u16* Bw = p.W + OFF_F2 + l * 32768;
      const float* fb = p.f2_b + l * 128;
      const int col = w * 16 + lr;
      floatx4 acc = FZ;
#pragma unroll
      for (int k0 = 0; k0 < 256; k0 += 32) {
        short8_t a = *(const short8_t*)&sm.g.FF1[lr][k0 + quad * 8];
        short8_t b = *(const short8_t*)&Bw[(size_t)col * 256 + k0 + quad * 8];
        acc = __builtin_amdgcn_mfma_f32_16x16x32_bf16(a, b, acc, 0, 0, 0);
      }
      const float bv = fb[col];
#pragma unroll
      for (int r = 0; r < 4; ++r)
        Xs[quad * 4 + r][col] += acc[r] + bv;
    }
    __syncthreads();
    if (l < 3) {
      // LN1(l+1) + qkv(l+1) -> qdst; Xs stays resident in LDS
      stage_x(p.ln1_s + (l + 1) * 128, p.ln1_b + (l + 1) * 128, true);
      __syncthreads();
      {
        const u16* Bw = p.W + OFF_QKV + (l + 1) * 49152;
        const float* qb = p.qkv_b + (l + 1) * 384;
        const int c0 = w * 48;
        floatx4 a0 = FZ, a1 = FZ, a2 = FZ;
#pragma unroll
        for (int k0 = 0; k0 < 128; k0 += 32) {
          short8_t a  = *(const short8_t*)&sm.g.A16[lr][k0 + quad * 8];
          short8_t b0 = *(const short8_t*)&Bw[(size_t)(c0 + lr) * 128 + k0 + quad * 8];
          short8_t b1 = *(const short8_t*)&Bw[(size_t)(c0 + 16 + lr) * 128 + k0 + quad * 8];
          short8_t b2 = *(const short8_t*)&Bw[(size_t)(c0 + 32 + lr) * 128 + k0 + quad * 8];
          a0 = __builtin_amdgcn_mfma_f32_16x16x32_bf16(a, b0, a0, 0, 0, 0);
          a1 = __builtin_amdgcn_mfma_f32_16x16x32_bf16(a, b1, a1, 0, 0, 0);
          a2 = __builtin_amdgcn_mfma_f32_16x16x32_bf16(a, b2, a2, 0, 0, 0);
        }
        __syncthreads();
#pragma unroll
        for (int r = 0; r < 4; ++r) {
          const int row = quad * 4 + r;
          sm.QS[row][c0 + lr]      = f2bf(a0[r] + qb[c0 + lr]);
          sm.QS[row][c0 + 16 + lr] = f2bf(a1[r] + qb[c0 + 16 + lr]);
          sm.QS[row][c0 + 32 + lr] = f2bf(a2[r] + qb[c0 + 32 + lr]);
        }
        __syncthreads();
        unsigned long long* d64 = (unsigned long long*)(qdst + (size_t)r0 * 384);
        const unsigned long long* s64 = (const unsigned long long*)&sm.QS[0][0];
        for (int j = t; j < 1536; j += BLK) st64(&d64[j], s64[j]);
      }
      gridbar(p.bar, grp, ++bar_k);   // next layer's attention gathers arbitrary rows
    } else {
      // --- heads: [lat1|b1] (N=192) -> lat2+normalize, beta ---
      stage_x(nullptr, nullptr, false);
      __syncthreads();
      {
        const int c0 = w * 32;
        if (c0 < 192) {
          const u16* Bw = p.W + OFF_LAT1;
          floatx4 a0 = FZ, a1 = FZ;
#pragma unroll
          for (int k0 = 0; k0 < 128; k0 += 32) {
            short8_t a  = *(const short8_t*)&sm.g.A16[lr][k0 + quad * 8];
            short8_t b0 = *(const short8_t*)&Bw[(size_t)(c0 + lr) * 128 + k0 + quad * 8];
            short8_t b1 = *(const short8_t*)&Bw[(size_t)(c0 + 16 + lr) * 128 + k0 + quad * 8];
            a0 = __builtin_amdgcn_mfma_f32_16x16x32_bf16(a, b0, a0, 0, 0, 0);
            a1 = __builtin_amdgcn_mfma_f32_16x16x32_bf16(a, b1, a1, 0, 0, 0);
          }
          const int cA = c0 + lr, cB = c0 + 16 + lr;
          const float bA = cA < 128 ? p.lat1_b[cA] : p.b1_b[cA - 128];
          const float bB = cB < 128 ? p.lat1_b[cB] : p.b1_b[cB - 128];
#pragma unroll
          for (int r = 0; r < 4; ++r) {
            const int row = quad * 4 + r;
            sm.g.FF1[row][cA] = f2bf(fmaxf(a0[r] + bA, 0.f));
            sm.g.FF1[row][cB] = f2bf(fmaxf(a1[r] + bB, 0.f));
          }
        }
      }
      __syncthreads();
      if (t < 256) {
        const int r = t >> 4, c = t & 15;
        float acc = p.lat2_b[c];
        const u16* gw = p.W + OFF_LAT2 + c * 128;
        for (int k = 0; k < 128; ++k) acc += bfu(sm.g.FF1[r][k]) * bfu(gw[k]);
        float ss = acc * acc;
        ss += __shfl_xor(ss, 1); ss += __shfl_xor(ss, 2);
        ss += __shfl_xor(ss, 4); ss += __shfl_xor(ss, 8);
        p.out[NT + (size_t)(r0 + r) * 16 + c] = acc / fmaxf(sqrtf(ss), 1e-12f);
        float v = 0.f;
#pragma unroll
        for (int i = 0; i < 4; ++i)
          v += bfu(sm.g.FF1[r][128 + c * 4 + i]) * p.b2_w[c * 4 + i];
        v += __shfl_xor(v, 1); v += __shfl_xor(v, 2);
        v += __shfl_xor(v, 4); v += __shfl_xor(v, 8);
        if (c == 0) {
          v += p.b2_b[0];
          const float beta = 1.f / (1.f + __expf(-v));
          p.out[r0 + r] = fminf(fmaxf(beta, 1e-6f), 1.f - 1e-6f);
        }
      }
    }
  }
}

extern "C" void kernel_launch(void* const* d_in, const int* in_sizes, int n_in,
                              void* d_out, int out_size, void* d_ws, size_t ws_size,
                              hipStream_t stream) {
  Prm prm;
  prm.xr    = (const float*)d_in[0];
  prm.in_w  = (const float*)d_in[2];  prm.in_b  = (const float*)d_in[3];
  prm.ln1_s = (const float*)d_in[4];  prm.ln1_b = (const float*)d_in[5];
  prm.qkv_w = (const float*)d_in[6];  prm.qkv_b = (const float*)d_in[7];
  prm.ao_w  = (const float*)d_in[8];  prm.ao_b  = (const float*)d_in[9];
  prm.ln2_s = (const float*)d_in[10]; prm.ln2_b = (const float*)d_in[11];
  prm.f1_w  = (const float*)d_in[12]; prm.f1_b  = (const float*)d_in[13];
  prm.f2_w  = (const float*)d_in[14]; prm.f2_b  = (const float*)d_in[15];
  prm.lat1_w= (const float*)d_in[16]; prm.lat1_b= (const float*)d_in[17];
  prm.lat2_w= (const float*)d_in[18]; prm.lat2_b= (const float*)d_in[19];
  prm.b1_w  = (const float*)d_in[20]; prm.b1_b  = (const float*)d_in[21];
  prm.b2_w  = (const float*)d_in[22]; prm.b2_b  = (const float*)d_in[23];
  prm.out   = (float*)d_out;

  char* pw = (char*)d_ws;
  prm.W    = (u16*)pw;   pw += ((size_t)W_TOTAL * 2 + 255) & ~(size_t)255;
  for (int i = 0; i < 4; ++i) { prm.QKV[i] = (u16*)pw; pw += (size_t)NT * 384 * 2; }
  prm.bar  = (int*)pw;   pw += 2048;           // root + 8 group lines (64B apart)

  hipMemsetAsync(prm.bar, 0, 2048, stream);
  fused_kernel<<<GRID, BLK, 0, stream>>>(prm);
}